// Round 1
// baseline (559.897 us; speedup 1.0000x reference)
//
#include <hip/hip_runtime.h>
#include <math.h>

#define DIM 256
#define KCODES 1024
#define BM 64
#define BN 64
#define BD 32
#define PAD 4

// ---------------------------------------------------------------------------
// Kernel A: per-code squared norms ||e_k||^2  -> ws[0..1023]
// ---------------------------------------------------------------------------
__global__ __launch_bounds__(64) void vq_norms_kernel(
    const float* __restrict__ E, float* __restrict__ enorm) {
  const int k = blockIdx.x;
  const int t = threadIdx.x;
  const float4 v = *reinterpret_cast<const float4*>(&E[k * DIM + t * 4]);
  float s = v.x * v.x + v.y * v.y + v.z * v.z + v.w * v.w;
#pragma unroll
  for (int off = 32; off >= 1; off >>= 1) s += __shfl_down(s, off);
  if (t == 0) enorm[k] = s;
}

// ---------------------------------------------------------------------------
// Kernel B: main — per 64-row block: argmin_k(||e||^2 - 2 x.e), gather, STE,
// loss partial.  16x16 threads, 4x4 microtile, fp32 vector FMA.
// ---------------------------------------------------------------------------
__global__ __launch_bounds__(256) void vq_main_kernel(
    const float* __restrict__ X, const float* __restrict__ E,
    const float* __restrict__ enorm, float* __restrict__ outq,
    float* __restrict__ partials) {
  __shared__ float Xs[BD][BM + PAD];  // transposed: [d][row]
  __shared__ float Es[BD][BN + PAD];  // transposed: [d][code]
  __shared__ int idxs[BM];
  __shared__ float lred[4];

  const int tid = threadIdx.x;
  const int tx = tid & 15;
  const int ty = tid >> 4;
  const int row0 = blockIdx.x * BM;

  float minv[4] = {INFINITY, INFINITY, INFINITY, INFINITY};
  int mini[4] = {0, 0, 0, 0};

  for (int kc = 0; kc < KCODES; kc += BN) {
    float acc[4][4] = {};
    for (int dc = 0; dc < DIM; dc += BD) {
      // stage 64x32 chunks of X and E, transposed into LDS
#pragma unroll
      for (int i = 0; i < 8; ++i) {
        const int c = tid + i * 256;  // 0..2047
        const int r = c >> 5;
        const int d = c & 31;
        Xs[d][r] = X[(row0 + r) * DIM + dc + d];
        Es[d][r] = E[(kc + r) * DIM + dc + d];
      }
      __syncthreads();
#pragma unroll
      for (int d = 0; d < BD; ++d) {
        const float4 xv = *reinterpret_cast<const float4*>(&Xs[d][ty * 4]);
        const float4 ev = *reinterpret_cast<const float4*>(&Es[d][tx * 4]);
        acc[0][0] += xv.x * ev.x; acc[0][1] += xv.x * ev.y;
        acc[0][2] += xv.x * ev.z; acc[0][3] += xv.x * ev.w;
        acc[1][0] += xv.y * ev.x; acc[1][1] += xv.y * ev.y;
        acc[1][2] += xv.y * ev.z; acc[1][3] += xv.y * ev.w;
        acc[2][0] += xv.z * ev.x; acc[2][1] += xv.z * ev.y;
        acc[2][2] += xv.z * ev.z; acc[2][3] += xv.z * ev.w;
        acc[3][0] += xv.w * ev.x; acc[3][1] += xv.w * ev.y;
        acc[3][2] += xv.w * ev.z; acc[3][3] += xv.w * ev.w;
      }
      __syncthreads();
    }
    // distance + running argmin (code ascending -> keeps first occurrence)
#pragma unroll
    for (int j = 0; j < 4; ++j) {
      const int code = kc + tx * 4 + j;
      const float en = enorm[code];
#pragma unroll
      for (int i = 0; i < 4; ++i) {
        const float dist = en - 2.0f * acc[i][j];
        if (dist < minv[i]) { minv[i] = dist; mini[i] = code; }
      }
    }
  }

  // reduce argmin across the 16 tx-lanes of each row group (within a wave)
#pragma unroll
  for (int off = 1; off < 16; off <<= 1) {
#pragma unroll
    for (int i = 0; i < 4; ++i) {
      const float ov = __shfl_xor(minv[i], off);
      const int oi = __shfl_xor(mini[i], off);
      if (ov < minv[i] || (ov == minv[i] && oi < mini[i])) {
        minv[i] = ov; mini[i] = oi;
      }
    }
  }
  if (tx == 0) {
#pragma unroll
    for (int i = 0; i < 4; ++i) idxs[ty * 4 + i] = mini[i];
  }
  __syncthreads();

  // gather + STE + loss partial.  tid indexes the 256 dims (coalesced).
  float lsum = 0.0f;
  for (int r = 0; r < BM; ++r) {
    const int code = idxs[r];
    const float e = E[code * DIM + tid];
    const float x = X[(row0 + r) * DIM + tid];
    const float dqx = e - x;                    // quantized - inputs
    outq[(row0 + r) * DIM + tid] = x + dqx;     // STE: inputs + (q - inputs)
    lsum += dqx * dqx;
  }
#pragma unroll
  for (int off = 32; off >= 1; off >>= 1) lsum += __shfl_down(lsum, off);
  if ((tid & 63) == 0) lred[tid >> 6] = lsum;
  __syncthreads();
  if (tid == 0)
    partials[blockIdx.x] = lred[0] + lred[1] + lred[2] + lred[3];
}

// ---------------------------------------------------------------------------
// Kernel C: deterministic loss reduction over 1024 block partials
// ---------------------------------------------------------------------------
__global__ __launch_bounds__(256) void vq_finalize_kernel(
    const float* __restrict__ partials, float* __restrict__ out_loss,
    float inv_count) {
  const int tid = threadIdx.x;
  float s = partials[tid] + partials[tid + 256] + partials[tid + 512] +
            partials[tid + 768];
#pragma unroll
  for (int off = 32; off >= 1; off >>= 1) s += __shfl_down(s, off);
  __shared__ float w[4];
  if ((tid & 63) == 0) w[tid >> 6] = s;
  __syncthreads();
  if (tid == 0) {
    const float m = (w[0] + w[1] + w[2] + w[3]) * inv_count;
    out_loss[0] = m + 0.25f * m;  // q_loss + commitment * e_loss
  }
}

extern "C" void kernel_launch(void* const* d_in, const int* in_sizes, int n_in,
                              void* d_out, int out_size, void* d_ws,
                              size_t ws_size, hipStream_t stream) {
  const float* X = (const float*)d_in[0];   // [16,4096,256] fp32
  const float* E = (const float*)d_in[1];   // [1024,256] fp32
  float* out = (float*)d_out;               // [0]=loss, [1..]=quantized

  float* enorm = (float*)d_ws;              // 1024 floats
  float* partials = enorm + KCODES;         // nblocks floats

  const int nrows = in_sizes[0] / DIM;      // 65536
  const int nblocks = nrows / BM;           // 1024

  vq_norms_kernel<<<KCODES, 64, 0, stream>>>(E, enorm);
  vq_main_kernel<<<nblocks, 256, 0, stream>>>(X, E, enorm, out + 1, partials);
  vq_finalize_kernel<<<1, 256, 0, stream>>>(
      partials, out, 1.0f / (float)in_sizes[0]);
}

// Round 2
// 177.924 us; speedup vs baseline: 3.1468x; 3.1468x over previous
//
#include <hip/hip_runtime.h>
#include <math.h>

#define DIM 256
#define KCODES 1024
#define BM 64

typedef __attribute__((ext_vector_type(8))) short bf16x8;
typedef __attribute__((ext_vector_type(4))) float f32x4;
typedef __attribute__((ext_vector_type(8))) unsigned short u16x8;
typedef __attribute__((ext_vector_type(4))) unsigned short u16x4;

__device__ inline unsigned short f2bf(float x) {
  union { float f; unsigned u; } v;
  v.f = x;
  return (unsigned short)((v.u + 0x8000u) >> 16);  // round-half-up, fine here
}

// ---------------------------------------------------------------------------
// Prep: per-code ||e||^2 (fp32) and bf16 copy of the codebook.
// ---------------------------------------------------------------------------
__global__ __launch_bounds__(64) void vq_prep_kernel(
    const float* __restrict__ E, float* __restrict__ enorm,
    unsigned short* __restrict__ Eb) {
  const int k = blockIdx.x;
  const int t = threadIdx.x;
  const float4 v = *reinterpret_cast<const float4*>(&E[k * DIM + t * 4]);
  u16x4 o;
  o[0] = f2bf(v.x); o[1] = f2bf(v.y); o[2] = f2bf(v.z); o[3] = f2bf(v.w);
  *reinterpret_cast<u16x4*>(&Eb[k * DIM + t * 4]) = o;
  float s = v.x * v.x + v.y * v.y + v.z * v.z + v.w * v.w;
#pragma unroll
  for (int off = 32; off >= 1; off >>= 1) s += __shfl_down(s, off);
  if (t == 0) enorm[k] = s;
}

// ---------------------------------------------------------------------------
// Main: 64 rows/block. A (X rows, bf16) register-resident per wave; codebook
// chunks (64 codes x 256 dims bf16) staged in swizzled LDS; distances via
// mfma_f32_16x16x32_bf16 with C initialized to -||e||^2/2 so dist = -2*acc.
// Each wave owns 16 of the 64 codes in a chunk (all 64 rows).
// ---------------------------------------------------------------------------
__global__ __launch_bounds__(256) void vq_main_kernel(
    const float* __restrict__ X, const float* __restrict__ E,
    const unsigned short* __restrict__ Eb, const float* __restrict__ enorm,
    float* __restrict__ outq, float* __restrict__ partials) {
  __shared__ unsigned short Es[BM * DIM];  // 32KB, XOR-swizzled rows
  __shared__ float fminv[4][BM];
  __shared__ int fmini[4][BM];
  __shared__ int idxs[BM];
  __shared__ float lred[4];

  const int tid = threadIdx.x;
  const int w = tid >> 6;        // wave id -> owns codes w*16..w*16+15 of chunk
  const int lane = tid & 63;
  const int lr = lane & 15;      // A-row within tile / B,C code within tile
  const int lk = lane >> 4;      // k-group (0..3)
  const int row0 = blockIdx.x * BM;

  // ---- A: 64 rows x 256 dims, fp32 global -> bf16 fragments in registers
  // frag layout (16x16x32): lane holds row (mt*16+lr), k = ks*32 + lk*8 + 0..7
  bf16x8 Afrag[4][8];
#pragma unroll
  for (int mt = 0; mt < 4; ++mt) {
    const float* xrow = &X[(size_t)(row0 + mt * 16 + lr) * DIM];
#pragma unroll
    for (int ks = 0; ks < 8; ++ks) {
      const int k0 = ks * 32 + lk * 8;
      const float4 a = *reinterpret_cast<const float4*>(&xrow[k0]);
      const float4 b = *reinterpret_cast<const float4*>(&xrow[k0 + 4]);
      bf16x8 f;
      f[0] = (short)f2bf(a.x); f[1] = (short)f2bf(a.y);
      f[2] = (short)f2bf(a.z); f[3] = (short)f2bf(a.w);
      f[4] = (short)f2bf(b.x); f[5] = (short)f2bf(b.y);
      f[6] = (short)f2bf(b.z); f[7] = (short)f2bf(b.w);
      Afrag[mt][ks] = f;
    }
  }

  float minv[16];
  int mini[16];
#pragma unroll
  for (int i = 0; i < 16; ++i) { minv[i] = INFINITY; mini[i] = 0; }

  for (int kc = 0; kc < KCODES; kc += 64) {
    __syncthreads();  // previous chunk's reads done before overwrite
    // stage 64 codes x 256 dims bf16 into LDS, swizzled: byte ^= (row&7)<<4
#pragma unroll
    for (int i = 0; i < 8; ++i) {
      const int grp = i * 256 + tid;  // 0..2047 groups of 8 bf16
      const int r = grp >> 5;
      const int g = grp & 31;
      const u16x8 v =
          *reinterpret_cast<const u16x8*>(&Eb[(size_t)(kc + r) * DIM + g * 8]);
      const int byte = (r * 512 + g * 16) ^ ((r & 7) << 4);
      *reinterpret_cast<u16x8*>(reinterpret_cast<char*>(Es) + byte) = v;
    }
    __syncthreads();

    const int code = kc + w * 16 + lr;
    const float en = enorm[code];
    f32x4 acc[4];
#pragma unroll
    for (int mt = 0; mt < 4; ++mt) {
      acc[mt][0] = -0.5f * en; acc[mt][1] = -0.5f * en;
      acc[mt][2] = -0.5f * en; acc[mt][3] = -0.5f * en;
    }
#pragma unroll
    for (int ks = 0; ks < 8; ++ks) {
      const int c = w * 16 + lr;
      const int byte = (c * 512 + (ks * 32 + lk * 8) * 2) ^ ((lr & 7) << 4);
      const bf16x8 bfrag = *reinterpret_cast<const bf16x8*>(
          reinterpret_cast<const char*>(Es) + byte);
#pragma unroll
      for (int mt = 0; mt < 4; ++mt)
        acc[mt] = __builtin_amdgcn_mfma_f32_16x16x32_bf16(Afrag[mt][ks], bfrag,
                                                          acc[mt], 0, 0, 0);
    }
    // running argmin; codes ascend per lane across chunks -> strict < keeps
    // the smallest index (first occurrence)
#pragma unroll
    for (int mt = 0; mt < 4; ++mt)
#pragma unroll
      for (int r = 0; r < 4; ++r) {
        const float dist = -2.0f * acc[mt][r];
        const int ri = mt * 4 + r;  // row mt*16 + lk*4 + r
        if (dist < minv[ri]) { minv[ri] = dist; mini[ri] = code; }
      }
  }

  // reduce across the 16 code-lanes (lr); tie -> lower index
#pragma unroll
  for (int off = 1; off < 16; off <<= 1) {
#pragma unroll
    for (int ri = 0; ri < 16; ++ri) {
      const float ov = __shfl_xor(minv[ri], off);
      const int oi = __shfl_xor(mini[ri], off);
      if (ov < minv[ri] || (ov == minv[ri] && oi < mini[ri])) {
        minv[ri] = ov; mini[ri] = oi;
      }
    }
  }
  if (lr == 0) {
#pragma unroll
    for (int mt = 0; mt < 4; ++mt)
#pragma unroll
      for (int r = 0; r < 4; ++r) {
        fminv[w][mt * 16 + lk * 4 + r] = minv[mt * 4 + r];
        fmini[w][mt * 16 + lk * 4 + r] = mini[mt * 4 + r];
      }
  }
  __syncthreads();
  if (tid < BM) {
    float bv = fminv[0][tid];
    int bi = fmini[0][tid];
#pragma unroll
    for (int ww = 1; ww < 4; ++ww) {
      const float v = fminv[ww][tid];
      const int i = fmini[ww][tid];
      if (v < bv || (v == bv && i < bi)) { bv = v; bi = i; }
    }
    idxs[tid] = bi;
  }
  __syncthreads();

  // gather + STE + loss partial, exact fp32. tid covers the 256 dims.
  float lsum = 0.0f;
  for (int r = 0; r < BM; ++r) {
    const int code = idxs[r];
    const float e = E[(size_t)code * DIM + tid];
    const float x = X[(size_t)(row0 + r) * DIM + tid];
    const float dqx = e - x;
    outq[(size_t)(row0 + r) * DIM + tid] = x + dqx;
    lsum += dqx * dqx;
  }
#pragma unroll
  for (int off = 32; off >= 1; off >>= 1) lsum += __shfl_down(lsum, off);
  if ((tid & 63) == 0) lred[tid >> 6] = lsum;
  __syncthreads();
  if (tid == 0)
    partials[blockIdx.x] = lred[0] + lred[1] + lred[2] + lred[3];
}

// ---------------------------------------------------------------------------
// Deterministic loss reduction over 1024 block partials
// ---------------------------------------------------------------------------
__global__ __launch_bounds__(256) void vq_finalize_kernel(
    const float* __restrict__ partials, float* __restrict__ out_loss,
    float inv_count) {
  const int tid = threadIdx.x;
  float s = partials[tid] + partials[tid + 256] + partials[tid + 512] +
            partials[tid + 768];
#pragma unroll
  for (int off = 32; off >= 1; off >>= 1) s += __shfl_down(s, off);
  __shared__ float w[4];
  if ((tid & 63) == 0) w[tid >> 6] = s;
  __syncthreads();
  if (tid == 0) {
    const float m = (w[0] + w[1] + w[2] + w[3]) * inv_count;
    out_loss[0] = m + 0.25f * m;  // q_latent + commitment * e_latent
  }
}

extern "C" void kernel_launch(void* const* d_in, const int* in_sizes, int n_in,
                              void* d_out, int out_size, void* d_ws,
                              size_t ws_size, hipStream_t stream) {
  const float* X = (const float*)d_in[0];  // [16,4096,256] fp32
  const float* E = (const float*)d_in[1];  // [1024,256] fp32
  float* out = (float*)d_out;              // [0]=loss, [1..]=quantized

  float* enorm = (float*)d_ws;                       // 1024 f32
  float* partials = enorm + KCODES;                  // 1024 f32
  unsigned short* Eb = (unsigned short*)(partials + 1024);  // 1024*256 bf16

  const int nrows = in_sizes[0] / DIM;  // 65536
  const int nblocks = nrows / BM;       // 1024

  vq_prep_kernel<<<KCODES, 64, 0, stream>>>(E, enorm, Eb);
  vq_main_kernel<<<nblocks, 256, 0, stream>>>(X, E, Eb, enorm, out + 1,
                                              partials);
  vq_finalize_kernel<<<1, 256, 0, stream>>>(partials, out,
                                            1.0f / (float)in_sizes[0]);
}

// Round 3
// 173.159 us; speedup vs baseline: 3.2334x; 1.0275x over previous
//
#include <hip/hip_runtime.h>
#include <math.h>

#define DIM 256
#define KCODES 1024
#define BM 64

typedef __attribute__((ext_vector_type(8))) short bf16x8;
typedef __attribute__((ext_vector_type(4))) float f32x4;
typedef __attribute__((ext_vector_type(4))) unsigned short u16x4;

__device__ inline unsigned short f2bf(float x) {
  union { float f; unsigned u; } v;
  v.f = x;
  return (unsigned short)((v.u + 0x8000u) >> 16);
}

// ---------------------------------------------------------------------------
// Prep: enormh[k] = -0.5*||e_k||^2, and codebook rearranged into MFMA
// B-fragment order: byte addr = (c*8+ks)*1024 + lane*16, lane = lk*16+lr,
// holding code c*16+lr, dims ks*32+lk*8 .. +7 (bf16).
// ---------------------------------------------------------------------------
__global__ __launch_bounds__(64) void vq_prep_kernel(
    const float* __restrict__ E, float* __restrict__ enormh,
    unsigned short* __restrict__ Ef) {
  const int k = blockIdx.x;   // code
  const int t = threadIdx.x;  // dims 4t..4t+3
  const float4 v = *reinterpret_cast<const float4*>(&E[k * DIM + t * 4]);
  u16x4 o;
  o[0] = f2bf(v.x); o[1] = f2bf(v.y); o[2] = f2bf(v.z); o[3] = f2bf(v.w);
  const int ks = t >> 3;
  const int lk = (t >> 1) & 3;
  const size_t byte = (size_t)(((k >> 4) * 8 + ks) * 1024) +
                      (size_t)((lk * 16 + (k & 15)) * 16) + (size_t)((t & 1) * 8);
  *reinterpret_cast<u16x4*>(reinterpret_cast<char*>(Ef) + byte) = o;
  float s = v.x * v.x + v.y * v.y + v.z * v.z + v.w * v.w;
#pragma unroll
  for (int off = 32; off >= 1; off >>= 1) s += __shfl_down(s, off);
  if (t == 0) enormh[k] = -0.5f * s;
}

// ---------------------------------------------------------------------------
// Main: 64 rows/block, 4 waves, NO LDS / NO barriers in the hot loop.
// A (64x256 bf16) register-resident; B fragments streamed from L2 in
// fragment order; argmax of score = x.e - ||e||^2/2  (== argmin distance).
// Wave w covers code-tiles c = w + 4*t16 (codes ascend per lane -> strict
// compare keeps first occurrence).
// ---------------------------------------------------------------------------
__global__ __launch_bounds__(256, 2) void vq_argmin_kernel(
    const float* __restrict__ X, const unsigned short* __restrict__ Ef,
    const float* __restrict__ enormh, int* __restrict__ idx_out) {
  __shared__ float fmax_s[4][BM];
  __shared__ int fidx_s[4][BM];

  const int tid = threadIdx.x;
  const int w = tid >> 6;
  const int lane = tid & 63;
  const int lr = lane & 15;
  const int lk = lane >> 4;
  const int row0 = blockIdx.x * BM;

  // A fragments: lane holds row mt*16+lr, k = ks*32 + lk*8 + j
  bf16x8 Afrag[4][8];
#pragma unroll
  for (int mt = 0; mt < 4; ++mt) {
    const float* xrow = &X[(size_t)(row0 + mt * 16 + lr) * DIM];
#pragma unroll
    for (int ks = 0; ks < 8; ++ks) {
      const int k0 = ks * 32 + lk * 8;
      const float4 a = *reinterpret_cast<const float4*>(&xrow[k0]);
      const float4 b = *reinterpret_cast<const float4*>(&xrow[k0 + 4]);
      bf16x8 f;
      f[0] = (short)f2bf(a.x); f[1] = (short)f2bf(a.y);
      f[2] = (short)f2bf(a.z); f[3] = (short)f2bf(a.w);
      f[4] = (short)f2bf(b.x); f[5] = (short)f2bf(b.y);
      f[6] = (short)f2bf(b.z); f[7] = (short)f2bf(b.w);
      Afrag[mt][ks] = f;
    }
  }

  // prefetch this lane's -||e||^2/2 for its 16 tiles
  float enh[16];
#pragma unroll
  for (int t16 = 0; t16 < 16; ++t16)
    enh[t16] = enormh[(w + 4 * t16) * 16 + lr];

  float maxv[16];
  int mini[16];
#pragma unroll
  for (int i = 0; i < 16; ++i) { maxv[i] = -INFINITY; mini[i] = 0; }

  const char* efbase = reinterpret_cast<const char*>(Ef) + lane * 16;

#pragma unroll
  for (int t16 = 0; t16 < 16; ++t16) {
    const int c = w + t16 * 4;
    const char* base = efbase + (size_t)c * 8192;
    f32x4 acc[4];
#pragma unroll
    for (int mt = 0; mt < 4; ++mt) {
      acc[mt][0] = enh[t16]; acc[mt][1] = enh[t16];
      acc[mt][2] = enh[t16]; acc[mt][3] = enh[t16];
    }
#pragma unroll
    for (int ks = 0; ks < 8; ++ks) {
      const bf16x8 bfrag =
          *reinterpret_cast<const bf16x8*>(base + ks * 1024);
#pragma unroll
      for (int mt = 0; mt < 4; ++mt)
        acc[mt] = __builtin_amdgcn_mfma_f32_16x16x32_bf16(Afrag[mt][ks], bfrag,
                                                          acc[mt], 0, 0, 0);
    }
    const int code = c * 16 + lr;
#pragma unroll
    for (int mt = 0; mt < 4; ++mt)
#pragma unroll
      for (int r = 0; r < 4; ++r) {
        const float s = acc[mt][r];
        const int ri = mt * 4 + r;  // row mt*16 + lk*4 + r
        if (s > maxv[ri]) { maxv[ri] = s; mini[ri] = code; }
      }
  }

  // reduce across the 16 code-lanes (lr); max score, tie -> lower code
#pragma unroll
  for (int off = 1; off < 16; off <<= 1) {
#pragma unroll
    for (int ri = 0; ri < 16; ++ri) {
      const float ov = __shfl_xor(maxv[ri], off);
      const int oi = __shfl_xor(mini[ri], off);
      if (ov > maxv[ri] || (ov == maxv[ri] && oi < mini[ri])) {
        maxv[ri] = ov; mini[ri] = oi;
      }
    }
  }
  if (lr == 0) {
#pragma unroll
    for (int mt = 0; mt < 4; ++mt)
#pragma unroll
      for (int r = 0; r < 4; ++r) {
        fmax_s[w][mt * 16 + lk * 4 + r] = maxv[mt * 4 + r];
        fidx_s[w][mt * 16 + lk * 4 + r] = mini[mt * 4 + r];
      }
  }
  __syncthreads();
  if (tid < BM) {
    float bv = fmax_s[0][tid];
    int bi = fidx_s[0][tid];
#pragma unroll
    for (int ww = 1; ww < 4; ++ww) {
      const float v = fmax_s[ww][tid];
      const int i = fidx_s[ww][tid];
      if (v > bv || (v == bv && i < bi)) { bv = v; bi = i; }
    }
    idx_out[row0 + tid] = bi;
  }
}

// ---------------------------------------------------------------------------
// Epilogue: gather + STE + loss partials. 16 rows/block, fully coalesced
// float4 streaming, exact fp32 (matches reference op order).
// ---------------------------------------------------------------------------
__global__ __launch_bounds__(256) void vq_epilogue_kernel(
    const float* __restrict__ X, const float* __restrict__ E,
    const int* __restrict__ idx, float* __restrict__ outq,
    float* __restrict__ partials) {
  const int tid = threadIdx.x;
  const int r = blockIdx.x * 16 + (tid >> 4);
  const int code = idx[r];
  const float* erow = &E[(size_t)code * DIM];
  const float* xrow = &X[(size_t)r * DIM];
  float* orow = &outq[(size_t)r * DIM];
  float lsum = 0.0f;
#pragma unroll
  for (int i = 0; i < 4; ++i) {
    const int d = (tid & 15) * 4 + i * 64;
    const float4 e = *reinterpret_cast<const float4*>(&erow[d]);
    const float4 x = *reinterpret_cast<const float4*>(&xrow[d]);
    const float dx0 = e.x - x.x, dx1 = e.y - x.y;
    const float dx2 = e.z - x.z, dx3 = e.w - x.w;
    float4 o;
    o.x = x.x + dx0; o.y = x.y + dx1; o.z = x.z + dx2; o.w = x.w + dx3;
    *reinterpret_cast<float4*>(&orow[d]) = o;
    lsum += dx0 * dx0 + dx1 * dx1 + dx2 * dx2 + dx3 * dx3;
  }
#pragma unroll
  for (int off = 32; off >= 1; off >>= 1) lsum += __shfl_down(lsum, off);
  __shared__ float lred[4];
  if ((tid & 63) == 0) lred[tid >> 6] = lsum;
  __syncthreads();
  if (tid == 0)
    partials[blockIdx.x] = lred[0] + lred[1] + lred[2] + lred[3];
}

// ---------------------------------------------------------------------------
// Deterministic loss reduction over nparts block partials
// ---------------------------------------------------------------------------
__global__ __launch_bounds__(256) void vq_finalize_kernel(
    const float* __restrict__ partials, float* __restrict__ out_loss,
    int nparts, float inv_count) {
  const int tid = threadIdx.x;
  float s = 0.0f;
  for (int i = tid; i < nparts; i += 256) s += partials[i];
#pragma unroll
  for (int off = 32; off >= 1; off >>= 1) s += __shfl_down(s, off);
  __shared__ float w[4];
  if ((tid & 63) == 0) w[tid >> 6] = s;
  __syncthreads();
  if (tid == 0) {
    const float m = (w[0] + w[1] + w[2] + w[3]) * inv_count;
    out_loss[0] = m + 0.25f * m;  // q_latent + commitment * e_latent
  }
}

extern "C" void kernel_launch(void* const* d_in, const int* in_sizes, int n_in,
                              void* d_out, int out_size, void* d_ws,
                              size_t ws_size, hipStream_t stream) {
  const float* X = (const float*)d_in[0];  // [16,4096,256] fp32
  const float* E = (const float*)d_in[1];  // [1024,256] fp32
  float* out = (float*)d_out;              // [0]=loss, [1..]=quantized

  char* ws = (char*)d_ws;
  float* enormh = (float*)ws;                       // @0KB: 1024 f32
  float* partials = (float*)(ws + 16 * 1024);      // @16KB: up to 4096 f32
  int* idx = (int*)(ws + 32 * 1024);               // @32KB: 65536 int
  unsigned short* Ef = (unsigned short*)(ws + 320 * 1024);  // @320KB: 512KB

  const int nrows = in_sizes[0] / DIM;  // 65536
  const int nb_main = nrows / BM;       // 1024
  const int nb_epi = nrows / 16;        // 4096

  vq_prep_kernel<<<KCODES, 64, 0, stream>>>(E, enormh, Ef);
  vq_argmin_kernel<<<nb_main, 256, 0, stream>>>(X, Ef, enormh, idx);
  vq_epilogue_kernel<<<nb_epi, 256, 0, stream>>>(X, E, idx, out + 1, partials);
  vq_finalize_kernel<<<1, 256, 0, stream>>>(partials, out, nb_epi,
                                            1.0f / (float)in_sizes[0]);
}

// Round 4
// 123.774 us; speedup vs baseline: 4.5235x; 1.3990x over previous
//
#include <hip/hip_runtime.h>
#include <math.h>

#define DIM 256
#define KCODES 1024
#define NCHUNK 16          // 1024 codes / 64 per chunk
#define CHUNK_BYTES 32768  // 64 codes x 256 dims x 2B (fragment order)

typedef __attribute__((ext_vector_type(8))) short bf16x8;
typedef __attribute__((ext_vector_type(4))) float f32x4;
typedef __attribute__((ext_vector_type(4))) unsigned short u16x4;

__device__ inline unsigned short f2bf(float x) {
  union { float f; unsigned u; } v;
  v.f = x;
  return (unsigned short)((v.u + 0x8000u) >> 16);
}

// ---------------------------------------------------------------------------
// Prep: enormh[k] = -0.5*||e_k||^2, codebook in MFMA B-fragment order:
// byte = ((k>>4)*8 + ks)*1024 + (lk*16 + (k&15))*16  holding dims ks*32+lk*8..
// ---------------------------------------------------------------------------
__global__ __launch_bounds__(64) void vq_prep_kernel(
    const float* __restrict__ E, float* __restrict__ enormh,
    unsigned short* __restrict__ Ef) {
  const int k = blockIdx.x;   // code
  const int t = threadIdx.x;  // dims 4t..4t+3
  const float4 v = *reinterpret_cast<const float4*>(&E[k * DIM + t * 4]);
  u16x4 o;
  o[0] = f2bf(v.x); o[1] = f2bf(v.y); o[2] = f2bf(v.z); o[3] = f2bf(v.w);
  const int ks = t >> 3;
  const int lk = (t >> 1) & 3;
  const size_t byte = (size_t)(((k >> 4) * 8 + ks) * 1024) +
                      (size_t)((lk * 16 + (k & 15)) * 16) +
                      (size_t)((t & 1) * 8);
  *reinterpret_cast<u16x4*>(reinterpret_cast<char*>(Ef) + byte) = o;
  float s = v.x * v.x + v.y * v.y + v.z * v.z + v.w * v.w;
#pragma unroll
  for (int off = 32; off >= 1; off >>= 1) s += __shfl_down(s, off);
  if (t == 0) enormh[k] = -0.5f * s;
}

// ---------------------------------------------------------------------------
// Main: 128 rows/block, 512 threads (8 waves = 2 row-groups x 4 code-tiles).
// A (X rows, bf16) register-resident per wave; B streamed via double-buffered
// global_load_lds (chunk = 64 codes = 32KB), one barrier per chunk.
// Score = x.e - ||e||^2/2 (argmax == argmin distance), strict compare with
// codes ascending per lane -> first-occurrence semantics.
// ---------------------------------------------------------------------------
__global__ __launch_bounds__(512, 2) void vq_argmin_kernel(
    const float* __restrict__ X, const unsigned short* __restrict__ Ef,
    const float* __restrict__ enormh, int* __restrict__ idx_out) {
  __shared__ char Bb[2][CHUNK_BYTES];  // 64 KB

  const int tid = threadIdx.x;
  const int w = tid >> 6;
  const int lane = tid & 63;
  const int lr = lane & 15;
  const int lk = lane >> 4;
  const int mgrp = w >> 2;  // row half (0/1)
  const int ct = w & 3;     // code-tile within chunk
  const int row0 = blockIdx.x * 128 + mgrp * 64;

  // ---- issue chunk-0 staging first (latency overlaps A setup)
  {
    const char* src = reinterpret_cast<const char*>(Ef);
#pragma unroll
    for (int i = 0; i < 4; ++i) {
      const int o = i * 8192 + tid * 16;
      __builtin_amdgcn_global_load_lds(
          (const __attribute__((address_space(1))) unsigned int*)(src + o),
          (__attribute__((address_space(3))) unsigned int*)(&Bb[0][o]), 16, 0,
          0);
    }
  }

  // ---- A: 64 rows x 256 dims per wave, fp32 -> bf16 fragments in registers
  bf16x8 Afrag[4][8];
#pragma unroll
  for (int mt = 0; mt < 4; ++mt) {
    const float* xrow = &X[(size_t)(row0 + mt * 16 + lr) * DIM];
#pragma unroll
    for (int ks = 0; ks < 8; ++ks) {
      const int k0 = ks * 32 + lk * 8;
      const float4 a = *reinterpret_cast<const float4*>(&xrow[k0]);
      const float4 b = *reinterpret_cast<const float4*>(&xrow[k0 + 4]);
      bf16x8 f;
      f[0] = (short)f2bf(a.x); f[1] = (short)f2bf(a.y);
      f[2] = (short)f2bf(a.z); f[3] = (short)f2bf(a.w);
      f[4] = (short)f2bf(b.x); f[5] = (short)f2bf(b.y);
      f[6] = (short)f2bf(b.z); f[7] = (short)f2bf(b.w);
      Afrag[mt][ks] = f;
    }
  }

  // per-lane -||e||^2/2 for this lane's code in each chunk
  float enh[NCHUNK];
#pragma unroll
  for (int t = 0; t < NCHUNK; ++t) enh[t] = enormh[t * 64 + ct * 16 + lr];

  float maxv[16];
  int mini[16];
#pragma unroll
  for (int i = 0; i < 16; ++i) { maxv[i] = -INFINITY; mini[i] = 0; }

  for (int t = 0; t < NCHUNK; ++t) {
    __syncthreads();  // drains vmcnt -> chunk t resident in Bb[t&1]
    if (t + 1 < NCHUNK) {  // issue chunk t+1 into the other buffer
      const char* src =
          reinterpret_cast<const char*>(Ef) + (size_t)(t + 1) * CHUNK_BYTES;
      char* dst = Bb[(t + 1) & 1];
#pragma unroll
      for (int i = 0; i < 4; ++i) {
        const int o = i * 8192 + tid * 16;
        __builtin_amdgcn_global_load_lds(
            (const __attribute__((address_space(1))) unsigned int*)(src + o),
            (__attribute__((address_space(3))) unsigned int*)(dst + o), 16, 0,
            0);
      }
    }
    const float e = enh[t];
    f32x4 acc[4];
#pragma unroll
    for (int mt = 0; mt < 4; ++mt) {
      acc[mt][0] = e; acc[mt][1] = e; acc[mt][2] = e; acc[mt][3] = e;
    }
#pragma unroll
    for (int ks = 0; ks < 8; ++ks) {
      const bf16x8 bf = *reinterpret_cast<const bf16x8*>(
          &Bb[t & 1][ct * 8192 + ks * 1024 + lane * 16]);
#pragma unroll
      for (int mt = 0; mt < 4; ++mt)
        acc[mt] = __builtin_amdgcn_mfma_f32_16x16x32_bf16(Afrag[mt][ks], bf,
                                                          acc[mt], 0, 0, 0);
    }
    const int code = t * 64 + ct * 16 + lr;
#pragma unroll
    for (int mt = 0; mt < 4; ++mt)
#pragma unroll
      for (int r = 0; r < 4; ++r) {
        const float s = acc[mt][r];
        const int ri = mt * 4 + r;  // row mt*16 + lk*4 + r
        if (s > maxv[ri]) { maxv[ri] = s; mini[ri] = code; }
      }
  }

  // reduce across the 16 code-lanes (lr); max score, tie -> lower code
#pragma unroll
  for (int off = 1; off < 16; off <<= 1) {
#pragma unroll
    for (int ri = 0; ri < 16; ++ri) {
      const float ov = __shfl_xor(maxv[ri], off);
      const int oi = __shfl_xor(mini[ri], off);
      if (ov > maxv[ri] || (ov == maxv[ri] && oi < mini[ri])) {
        maxv[ri] = ov; mini[ri] = oi;
      }
    }
  }

  __syncthreads();  // all B reads done -> safe to alias Bb for the finale
  float* fmax_s = reinterpret_cast<float*>(&Bb[0][0]);     // 8*64 floats
  int* fidx_s = reinterpret_cast<int*>(&Bb[0][4096]);      // 8*64 ints
  if (lr == 0) {
#pragma unroll
    for (int mt = 0; mt < 4; ++mt)
#pragma unroll
      for (int r = 0; r < 4; ++r) {
        fmax_s[w * 64 + mt * 16 + lk * 4 + r] = maxv[mt * 4 + r];
        fidx_s[w * 64 + mt * 16 + lk * 4 + r] = mini[mt * 4 + r];
      }
  }
  __syncthreads();
  if (tid < 128) {
    const int mg = tid >> 6;
    const int rr = tid & 63;
    float bv = fmax_s[(mg * 4) * 64 + rr];
    int bi = fidx_s[(mg * 4) * 64 + rr];
#pragma unroll
    for (int ww = 1; ww < 4; ++ww) {
      const float v = fmax_s[(mg * 4 + ww) * 64 + rr];
      const int i = fidx_s[(mg * 4 + ww) * 64 + rr];
      if (v > bv || (v == bv && i < bi)) { bv = v; bi = i; }
    }
    idx_out[blockIdx.x * 128 + tid] = bi;
  }
}

// ---------------------------------------------------------------------------
// Epilogue: gather + STE + loss partials. Streaming, exact fp32.
// ---------------------------------------------------------------------------
__global__ __launch_bounds__(256) void vq_epilogue_kernel(
    const float* __restrict__ X, const float* __restrict__ E,
    const int* __restrict__ idx, float* __restrict__ outq,
    float* __restrict__ partials) {
  const int tid = threadIdx.x;
  const int r = blockIdx.x * 16 + (tid >> 4);
  const int code = idx[r];
  const float* erow = &E[(size_t)code * DIM];
  const float* xrow = &X[(size_t)r * DIM];
  float* orow = &outq[(size_t)r * DIM];
  float lsum = 0.0f;
#pragma unroll
  for (int i = 0; i < 4; ++i) {
    const int d = (tid & 15) * 4 + i * 64;
    const float4 e = *reinterpret_cast<const float4*>(&erow[d]);
    const float4 x = *reinterpret_cast<const float4*>(&xrow[d]);
    const float dx0 = e.x - x.x, dx1 = e.y - x.y;
    const float dx2 = e.z - x.z, dx3 = e.w - x.w;
    float4 o;
    o.x = x.x + dx0; o.y = x.y + dx1; o.z = x.z + dx2; o.w = x.w + dx3;
    *reinterpret_cast<float4*>(&orow[d]) = o;
    lsum += dx0 * dx0 + dx1 * dx1 + dx2 * dx2 + dx3 * dx3;
  }
#pragma unroll
  for (int off = 32; off >= 1; off >>= 1) lsum += __shfl_down(lsum, off);
  __shared__ float lred[4];
  if ((tid & 63) == 0) lred[tid >> 6] = lsum;
  __syncthreads();
  if (tid == 0)
    partials[blockIdx.x] = lred[0] + lred[1] + lred[2] + lred[3];
}

// ---------------------------------------------------------------------------
// Deterministic loss reduction
// ---------------------------------------------------------------------------
__global__ __launch_bounds__(256) void vq_finalize_kernel(
    const float* __restrict__ partials, float* __restrict__ out_loss,
    int nparts, float inv_count) {
  const int tid = threadIdx.x;
  float s = 0.0f;
  for (int i = tid; i < nparts; i += 256) s += partials[i];
#pragma unroll
  for (int off = 32; off >= 1; off >>= 1) s += __shfl_down(s, off);
  __shared__ float w[4];
  if ((tid & 63) == 0) w[tid >> 6] = s;
  __syncthreads();
  if (tid == 0) {
    const float m = (w[0] + w[1] + w[2] + w[3]) * inv_count;
    out_loss[0] = m + 0.25f * m;  // q_latent + commitment * e_latent
  }
}

extern "C" void kernel_launch(void* const* d_in, const int* in_sizes, int n_in,
                              void* d_out, int out_size, void* d_ws,
                              size_t ws_size, hipStream_t stream) {
  const float* X = (const float*)d_in[0];  // [16,4096,256] fp32
  const float* E = (const float*)d_in[1];  // [1024,256] fp32
  float* out = (float*)d_out;              // [0]=loss, [1..]=quantized

  char* ws = (char*)d_ws;
  float* enormh = (float*)ws;                               // @0KB
  float* partials = (float*)(ws + 16 * 1024);               // @16KB
  int* idx = (int*)(ws + 32 * 1024);                        // @32KB (256KB)
  unsigned short* Ef = (unsigned short*)(ws + 320 * 1024);  // @320KB (512KB)

  const int nrows = in_sizes[0] / DIM;  // 65536
  const int nb_main = nrows / 128;      // 512
  const int nb_epi = nrows / 16;        // 4096

  vq_prep_kernel<<<KCODES, 64, 0, stream>>>(E, enormh, Ef);
  vq_argmin_kernel<<<nb_main, 512, 0, stream>>>(X, Ef, enormh, idx);
  vq_epilogue_kernel<<<nb_epi, 256, 0, stream>>>(X, E, idx, out + 1, partials);
  vq_finalize_kernel<<<1, 256, 0, stream>>>(partials, out, nb_epi,
                                            1.0f / (float)in_sizes[0]);
}